// Round 12
// baseline (732.395 us; speedup 1.0000x reference)
//
#include <hip/hip_runtime.h>
#include <hip/hip_bf16.h>

typedef __bf16 bf16x8 __attribute__((ext_vector_type(8)));
typedef __bf16 bf16x4 __attribute__((ext_vector_type(4)));
typedef float  f32x4  __attribute__((ext_vector_type(4)));

#define MFMA(a, b, c) __builtin_amdgcn_mfma_f32_16x16x32_bf16((a), (b), (c), 0, 0, 0)

__device__ inline unsigned int pkbf(float a, float b) {
    __bf16 x = (__bf16)a, y = (__bf16)b;
    return (unsigned int)*(unsigned short*)&x |
           ((unsigned int)*(unsigned short*)&y << 16);
}

// ---------------------------------------------------------------------------
// Batched weight transpose + cvt for the four 1024x1024 weights (1 launch).
// ---------------------------------------------------------------------------
__global__ __launch_bounds__(256) void transpose_cvt4(
    const float* __restrict__ s0, const float* __restrict__ s1,
    const float* __restrict__ s2, const float* __restrict__ s3,
    __bf16* __restrict__ d0, __bf16* __restrict__ d1,
    __bf16* __restrict__ d2, __bf16* __restrict__ d3)
{
    __shared__ float tile[32][33];
    const int z = blockIdx.z;
    const float* src = (z == 0) ? s0 : (z == 1) ? s1 : (z == 2) ? s2 : s3;
    __bf16* dst = (z == 0) ? d0 : (z == 1) ? d1 : (z == 2) ? d2 : d3;
    const int k0 = blockIdx.y * 32, n0 = blockIdx.x * 32;
    const int t = threadIdx.x;
    const int r = t >> 5, c = t & 31;
#pragma unroll
    for (int i = 0; i < 4; ++i)
        tile[r + i * 8][c] = src[(long)(k0 + r + i * 8) * 1024 + n0 + c];
    __syncthreads();
#pragma unroll
    for (int i = 0; i < 4; ++i)
        dst[(long)(n0 + r + i * 8) * 1024 + k0 + c] = (__bf16)tile[c][r + i * 8];
}

// src f32 [K][N] -> dst bf16 [N][K]  (w1 / w2)
__global__ __launch_bounds__(256) void transpose_cvt(
    const float* __restrict__ src, __bf16* __restrict__ dst, int Kd, int Nd)
{
    __shared__ float tile[32][33];
    const int k0 = blockIdx.y * 32, n0 = blockIdx.x * 32;
    const int t = threadIdx.x;
    const int r = t >> 5, c = t & 31;
#pragma unroll
    for (int i = 0; i < 4; ++i)
        tile[r + i * 8][c] = src[(long)(k0 + r + i * 8) * Nd + n0 + c];
    __syncthreads();
#pragma unroll
    for (int i = 0; i < 4; ++i)
        dst[(long)(n0 + r + i * 8) * Kd + k0 + c] = (__bf16)tile[c][r + i * 8];
}

// V [bh][2048][64] -> Vt [bh][64][2048]
__global__ __launch_bounds__(256) void transpose_v(
    const __bf16* __restrict__ V, __bf16* __restrict__ Vt)
{
    __shared__ __bf16 tile[32][33];
    const int bh = blockIdx.z;
    const int s0 = blockIdx.x * 32, d0 = blockIdx.y * 32;
    const int t = threadIdx.x, r = t >> 5, c = t & 31;
    const __bf16* Vp = V + (long)bh * 2048 * 64;
    __bf16* Tp = Vt + (long)bh * 64 * 2048;
#pragma unroll
    for (int i = 0; i < 4; ++i)
        tile[r + i * 8][c] = Vp[(long)(s0 + r + i * 8) * 64 + d0 + c];
    __syncthreads();
#pragma unroll
    for (int i = 0; i < 4; ++i)
        Tp[(long)(d0 + r + i * 8) * 2048 + s0 + c] = tile[c][r + i * 8];
}

// ---------------------------------------------------------------------------
// LayerNorm (torch: ddof=1 std, eps added to std), f32 in, bf16 out
// ---------------------------------------------------------------------------
__global__ __launch_bounds__(256) void ln_kernel(
    const float* __restrict__ in, const float* __restrict__ ga,
    const float* __restrict__ gb, __bf16* __restrict__ out)
{
    const int row = blockIdx.x;
    const int t = threadIdx.x;
    const float4 xv = *(const float4*)(in + (long)row * 1024 + t * 4);
    float s  = xv.x + xv.y + xv.z + xv.w;
    float sq = xv.x * xv.x + xv.y * xv.y + xv.z * xv.z + xv.w * xv.w;
#pragma unroll
    for (int off = 32; off; off >>= 1) {
        s  += __shfl_xor(s, off);
        sq += __shfl_xor(sq, off);
    }
    __shared__ float red[8];
    const int w = t >> 6;
    if ((t & 63) == 0) { red[w * 2] = s; red[w * 2 + 1] = sq; }
    __syncthreads();
    s  = red[0] + red[2] + red[4] + red[6];
    sq = red[1] + red[3] + red[5] + red[7];
    const float mean = s * (1.0f / 1024.0f);
    const float var  = fmaxf((sq - s * mean) * (1.0f / 1023.0f), 0.0f);
    const float dinv = 1.0f / (sqrtf(var) + 1e-6f);
    const float4 av = *(const float4*)(ga + t * 4);
    const float4 bv = *(const float4*)(gb + t * 4);
    bf16x4 o;
    o[0] = (__bf16)((xv.x - mean) * dinv * av.x + bv.x);
    o[1] = (__bf16)((xv.y - mean) * dinv * av.y + bv.y);
    o[2] = (__bf16)((xv.z - mean) * dinv * av.z + bv.z);
    o[3] = (__bf16)((xv.w - mean) * dinv * av.w + bv.w);
    *(bf16x4*)(out + (long)row * 1024 + t * 4) = o;
}

// ---------------------------------------------------------------------------
// GEMM 128x128 (R8 reg-staged dbuf, 1 barrier/step) — best measured config.
// MODE 0: QKV scatter; 1: +resid f32; 2: +bias ReLU bf16; 3: +bias+resid f32
// ---------------------------------------------------------------------------
template <int MODE>
__global__ __launch_bounds__(256) void gemm_bt(
    const __bf16* __restrict__ A, const __bf16* __restrict__ Bt,
    int M, int N, int K,
    const float* __restrict__ bias, const float* resid,
    float* outf, __bf16* __restrict__ outb,
    __bf16* __restrict__ qb, __bf16* __restrict__ kb, __bf16* __restrict__ vb)
{
    __shared__ __align__(16) __bf16 Alds[2][128 * 32];
    __shared__ __align__(16) __bf16 Blds[2][128 * 32];

    const int t = threadIdx.x;
    const int lane = t & 63, w = t >> 6;
    const int wr = w >> 1, wc = w & 1;
    const int g = lane >> 4, l15 = lane & 15;

    const int nwg = gridDim.x * gridDim.y;
    const int hwid = blockIdx.y * gridDim.x + blockIdx.x;
    const int wid = (hwid & 7) * (nwg >> 3) + (hwid >> 3);
    const int bm = (wid / gridDim.x) * 128;
    const int bn = (wid % gridDim.x) * 128;

    const int cr = t >> 2;
    const int cc = (t & 3) * 8;
    const __bf16* Ag  = A  + (long)(bm + cr) * K + cc;
    const __bf16* Ag2 = Ag + (long)64 * K;
    const __bf16* Bg  = Bt + (long)(bn + cr) * K + cc;
    const __bf16* Bg2 = Bg + (long)64 * K;
    const int wof = cr * 32 + cc;

    f32x4 acc[4][4] = {};
    const int nk = K / 32;

    bf16x8 ra0 = *(const bf16x8*)(Ag);
    bf16x8 ra1 = *(const bf16x8*)(Ag2);
    bf16x8 rb0 = *(const bf16x8*)(Bg);
    bf16x8 rb1 = *(const bf16x8*)(Bg2);
    *(bf16x8*)(&Alds[0][wof])           = ra0;
    *(bf16x8*)(&Alds[0][wof + 64 * 32]) = ra1;
    *(bf16x8*)(&Blds[0][wof])           = rb0;
    *(bf16x8*)(&Blds[0][wof + 64 * 32]) = rb1;
    ra0 = *(const bf16x8*)(Ag  + 32);
    ra1 = *(const bf16x8*)(Ag2 + 32);
    rb0 = *(const bf16x8*)(Bg  + 32);
    rb1 = *(const bf16x8*)(Bg2 + 32);
    __syncthreads();

    for (int kt = 0; kt < nk; ++kt) {
        const int cur = kt & 1;
        if (kt + 1 < nk) {
            *(bf16x8*)(&Alds[cur ^ 1][wof])           = ra0;
            *(bf16x8*)(&Alds[cur ^ 1][wof + 64 * 32]) = ra1;
            *(bf16x8*)(&Blds[cur ^ 1][wof])           = rb0;
            *(bf16x8*)(&Blds[cur ^ 1][wof + 64 * 32]) = rb1;
            if (kt + 2 < nk) {
                const long ko = (long)(kt + 2) * 32;
                ra0 = *(const bf16x8*)(Ag  + ko);
                ra1 = *(const bf16x8*)(Ag2 + ko);
                rb0 = *(const bf16x8*)(Bg  + ko);
                rb1 = *(const bf16x8*)(Bg2 + ko);
            }
        }
        const __bf16* Ab = &Alds[cur][0];
        const __bf16* Bb = &Blds[cur][0];
        bf16x8 af[4], bfr[4];
#pragma unroll
        for (int mi = 0; mi < 4; ++mi)
            af[mi] = *(const bf16x8*)(Ab + (wr * 64 + mi * 16 + l15) * 32 + g * 8);
#pragma unroll
        for (int ni = 0; ni < 4; ++ni)
            bfr[ni] = *(const bf16x8*)(Bb + (wc * 64 + ni * 16 + l15) * 32 + g * 8);
#pragma unroll
        for (int mi = 0; mi < 4; ++mi)
#pragma unroll
            for (int ni = 0; ni < 4; ++ni)
                acc[mi][ni] = MFMA(af[mi], bfr[ni], acc[mi][ni]);
        __syncthreads();
    }

#pragma unroll
    for (int mi = 0; mi < 4; ++mi) {
#pragma unroll
        for (int ni = 0; ni < 4; ++ni) {
#pragma unroll
            for (int r = 0; r < 4; ++r) {
                const int gr = bm + wr * 64 + mi * 16 + g * 4 + r;
                const int gc = bn + wc * 64 + ni * 16 + l15;
                const float vacc = acc[mi][ni][r];
                if constexpr (MODE == 0) {
                    const int bufi = gc >> 10;
                    const int hd = gc & 1023;
                    const int h = hd >> 6, d = hd & 63;
                    const int b = gr >> 11, sx = gr & 2047;
                    __bf16* dst = (bufi == 0) ? qb : ((bufi == 1) ? kb : vb);
                    dst[((long)((b * 16 + h) * 2048 + sx)) * 64 + d] = (__bf16)vacc;
                } else if constexpr (MODE == 1) {
                    const long idx = (long)gr * N + gc;
                    outf[idx] = vacc + resid[idx];
                } else if constexpr (MODE == 2) {
                    const float y = fmaxf(vacc + bias[gc], 0.0f);
                    outb[(long)gr * N + gc] = (__bf16)y;
                } else {
                    const long idx = (long)gr * N + gc;
                    outf[idx] = vacc + bias[gc] + resid[idx];
                }
            }
        }
    }
}

// ---------------------------------------------------------------------------
// Flash attention — R8 body (best measured) with two changes:
// (1) __launch_bounds__(256,4): kernel fits 92 VGPR / 16.9KB LDS -> 4
//     blocks/CU resident (grid = exactly 4/CU), doubling cross-block TLP
//     that covers the 2 barriers/tile. (R3's spill was a 128-cap vs ~180
//     live regs; current body lives in 92.)
// (2) XCD bh-grouping (verified R7: FETCH 139->24MB): all 16 q-blocks of
//     8 heads per XCD -> K/V working set 4MB = one L2.
// ---------------------------------------------------------------------------
__global__ __launch_bounds__(256, 4) void attn_kernel(
    const __bf16* __restrict__ Q, const __bf16* __restrict__ Kk,
    const __bf16* __restrict__ Vt, const int* __restrict__ mask,
    __bf16* __restrict__ O)
{
    __shared__ __align__(16) char Klds[8192];
    __shared__ __align__(16) char Vlds[8192];
    __shared__ int mlds[64];
    __shared__ int tflag[32];

    const int t = threadIdx.x;
    const int lane = t & 63, w = t >> 6;
    const int g = lane >> 4, l15 = lane & 15;
    const int bid = blockIdx.x;
    const int bh = (bid & 7) * 8 + ((bid >> 3) >> 4);   // 8 heads per XCD
    const int qt = (bid >> 3) & 15;
    const int b = bh >> 4, h = bh & 15;
    const int q0 = qt * 128 + w * 32;

    const __bf16* Qp = Q  + (long)bh * 2048 * 64;
    const __bf16* Kp = Kk + (long)bh * 2048 * 64;
    const __bf16* Vp = Vt + (long)bh * 64 * 2048;
    const int* mp = mask + b * 2048;

    {
        const int4* mi4 = (const int4*)(mp + t * 8);
        const int4 ma = mi4[0], mb = mi4[1];
        const int ok = (ma.x && ma.y && ma.z && ma.w &&
                        mb.x && mb.y && mb.z && mb.w) ? 1 : 0;
        const unsigned long long bal = __ballot(ok);
        if ((lane & 7) == 0)
            tflag[t >> 3] = (((bal >> lane) & 0xFFull) == 0xFFull) ? 1 : 0;
    }

    bf16x8 qreg[2][2];
#pragma unroll
    for (int qf = 0; qf < 2; ++qf)
#pragma unroll
        for (int kh = 0; kh < 2; ++kh)
            qreg[qf][kh] = *(const bf16x8*)(Qp + (long)(q0 + qf * 16 + l15) * 64 + kh * 32 + g * 8);

    bf16x8 vone;
#pragma unroll
    for (int j = 0; j < 8; ++j) vone[j] = (__bf16)1.0f;

    const float Csc = 0.18033688011112042f;   // 0.125 * log2(e)
    float m2_run[2] = {-1e30f, -1e30f};
    f32x4 la[2] = {};
    f32x4 ot[2][4] = {};

    const int sr0 = t >> 3;
    const int sce = (t & 7) * 8;
    const int swz0 = sr0 * 128 + (((t & 7) * 16) ^ ((sr0 & 7) << 4));
    const int swz1 = swz0 + 32 * 128;

    bf16x8 kr0 = *(const bf16x8*)(Kp + (long)sr0 * 64 + sce);
    bf16x8 kr1 = *(const bf16x8*)(Kp + (long)(sr0 + 32) * 64 + sce);
    bf16x8 vr0 = *(const bf16x8*)(Vp + (long)sr0 * 2048 + sce);
    bf16x8 vr1 = *(const bf16x8*)(Vp + (long)(sr0 + 32) * 2048 + sce);
    int mr = (t < 64) ? mp[t] : 0;

    for (int kc = 0; kc < 32; ++kc) {
        __syncthreads();
        *(bf16x8*)(Klds + swz0) = kr0;
        *(bf16x8*)(Klds + swz1) = kr1;
        *(bf16x8*)(Vlds + swz0) = vr0;
        *(bf16x8*)(Vlds + swz1) = vr1;
        if (t < 64) mlds[t] = mr;
        __syncthreads();
        if (kc < 31) {
            const int kv0 = (kc + 1) * 64;
            kr0 = *(const bf16x8*)(Kp + (long)(kv0 + sr0) * 64 + sce);
            kr1 = *(const bf16x8*)(Kp + (long)(kv0 + sr0 + 32) * 64 + sce);
            vr0 = *(const bf16x8*)(Vp + (long)sr0 * 2048 + kv0 + sce);
            vr1 = *(const bf16x8*)(Vp + (long)(sr0 + 32) * 2048 + kv0 + sce);
            if (t < 64) mr = mp[kv0 + t];
        }
        const bool fullv = (tflag[kc] != 0);

        bf16x8 kf[4][2];
#pragma unroll
        for (int f = 0; f < 4; ++f)
#pragma unroll
            for (int dh = 0; dh < 2; ++dh)
                kf[f][dh] = *(const bf16x8*)(Klds + (f * 16 + l15) * 128 +
                                             ((dh * 64 + g * 16) ^ ((l15 & 7) << 4)));
        f32x4 sf[2][4] = {};
        __builtin_amdgcn_s_setprio(1);
#pragma unroll
        for (int qf = 0; qf < 2; ++qf)
#pragma unroll
            for (int f = 0; f < 4; ++f) {
                sf[qf][f] = MFMA(kf[f][0], qreg[qf][0], sf[qf][f]);
                sf[qf][f] = MFMA(kf[f][1], qreg[qf][1], sf[qf][f]);
            }
        __builtin_amdgcn_s_setprio(0);

        bf16x8 av[4][2];
#pragma unroll
        for (int df = 0; df < 4; ++df) {
            const int row = (df * 16 + l15) * 128;
            const int sx = (l15 & 7) << 4;
#pragma unroll
            for (int hh = 0; hh < 2; ++hh) {
                const bf16x4 lo = *(const bf16x4*)(Vlds + row + ((hh * 64 + g * 8) ^ sx));
                const bf16x4 hi = *(const bf16x4*)(Vlds + row + ((hh * 64 + 32 + g * 8) ^ sx));
                bf16x8 a;
                a[0] = lo[0]; a[1] = lo[1]; a[2] = lo[2]; a[3] = lo[3];
                a[4] = hi[0]; a[5] = hi[1]; a[6] = hi[2]; a[7] = hi[3];
                av[df][hh] = a;
            }
        }

#pragma unroll
        for (int qf = 0; qf < 2; ++qf) {
            float s[16];
            if (fullv) {
#pragma unroll
                for (int i = 0; i < 16; ++i) s[i] = sf[qf][i >> 2][i & 3];
            } else {
                int mvv[16];
#pragma unroll
                for (int f = 0; f < 4; ++f) {
                    const int4 mq = *(const int4*)&mlds[f * 16 + g * 4];
                    mvv[f * 4 + 0] = mq.x; mvv[f * 4 + 1] = mq.y;
                    mvv[f * 4 + 2] = mq.z; mvv[f * 4 + 3] = mq.w;
                }
#pragma unroll
                for (int i = 0; i < 16; ++i)
                    s[i] = (mvv[i] == 0) ? -1e9f : sf[qf][i >> 2][i & 3];
            }
            float m01 = fmaxf(s[0], s[1]),   m23 = fmaxf(s[2], s[3]);
            float m45 = fmaxf(s[4], s[5]),   m67 = fmaxf(s[6], s[7]);
            float m89 = fmaxf(s[8], s[9]),   mab = fmaxf(s[10], s[11]);
            float mcd = fmaxf(s[12], s[13]), mef = fmaxf(s[14], s[15]);
            float mx = fmaxf(fmaxf(fmaxf(m01, m23), fmaxf(m45, m67)),
                             fmaxf(fmaxf(m89, mab), fmaxf(mcd, mef)));
            mx = fmaxf(mx, __shfl_xor(mx, 16));
            mx = fmaxf(mx, __shfl_xor(mx, 32));
            const float m2 = mx * Csc;
            if (!__all(m2 - m2_run[qf] <= 8.0f)) {
                const float m2n = fmaxf(m2_run[qf], m2);
                const float alpha = __builtin_amdgcn_exp2f(m2_run[qf] - m2n);
#pragma unroll
                for (int r = 0; r < 4; ++r) la[qf][r] *= alpha;
#pragma unroll
                for (int df = 0; df < 4; ++df)
#pragma unroll
                    for (int r = 0; r < 4; ++r) ot[qf][df][r] *= alpha;
                m2_run[qf] = m2n;
            }
            const float nm2 = -m2_run[qf];
            float p[16];
#pragma unroll
            for (int i = 0; i < 16; ++i)
                p[i] = __builtin_amdgcn_exp2f(__builtin_fmaf(s[i], Csc, nm2));

#pragma unroll
            for (int hh = 0; hh < 2; ++hh) {
                unsigned int pu[4] = {pkbf(p[hh * 8 + 0], p[hh * 8 + 1]),
                                      pkbf(p[hh * 8 + 2], p[hh * 8 + 3]),
                                      pkbf(p[hh * 8 + 4], p[hh * 8 + 5]),
                                      pkbf(p[hh * 8 + 6], p[hh * 8 + 7])};
                bf16x8 pf = *(bf16x8*)pu;   // slot j = P[sigma(g,j)][q=l15]
                __builtin_amdgcn_s_setprio(1);
#pragma unroll
                for (int df = 0; df < 4; ++df)
                    ot[qf][df] = MFMA(av[df][hh], pf, ot[qf][df]);
                la[qf] = MFMA(vone, pf, la[qf]);
                __builtin_amdgcn_s_setprio(0);
            }
        }
    }

#pragma unroll
    for (int qf = 0; qf < 2; ++qf) {
        const float inv = 1.0f / la[qf][0];
        const int q = q0 + qf * 16 + l15;
        __bf16* orow = O + (long)(b * 2048 + q) * 1024 + h * 64;
#pragma unroll
        for (int df = 0; df < 4; ++df)
#pragma unroll
            for (int rp = 0; rp < 2; ++rp) {
                const int d = df * 16 + g * 4 + rp * 2;
                *(unsigned int*)(orow + d) =
                    pkbf(ot[qf][df][rp * 2] * inv, ot[qf][df][rp * 2 + 1] * inv);
            }
    }
}

// ---------------------------------------------------------------------------
extern "C" void kernel_launch(void* const* d_in, const int* in_sizes, int n_in,
                              void* d_out, int out_size, void* d_ws, size_t ws_size,
                              hipStream_t stream)
{
    const float* x    = (const float*)d_in[0];
    const int*   mask = (const int*)  d_in[1];
    const float* wq   = (const float*)d_in[2];
    const float* wk   = (const float*)d_in[3];
    const float* wv   = (const float*)d_in[4];
    const float* wo   = (const float*)d_in[5];
    const float* w1   = (const float*)d_in[6];
    const float* b1   = (const float*)d_in[7];
    const float* w2   = (const float*)d_in[8];
    const float* b2   = (const float*)d_in[9];
    const float* l1a  = (const float*)d_in[10];
    const float* l1b  = (const float*)d_in[11];
    const float* l2a  = (const float*)d_in[12];
    const float* l2b  = (const float*)d_in[13];
    float* out = (float*)d_out;

    char* ws = (char*)d_ws;
    __bf16* wqkvT = (__bf16*)(ws);                       // [3072][1024]  6 MB
    __bf16* woT   = (__bf16*)(ws + 6291456);             // [1024][1024]  2 MB
    __bf16* w1T   = (__bf16*)(ws + 8388608);             // [4096][1024]  8 MB
    __bf16* w2T   = (__bf16*)(ws + 16777216);            // [1024][4096]  8 MB
    __bf16* xn    = (__bf16*)(ws + 25165824);            // [8192][1024] 16 MB (doubles as Vt)
    __bf16* Vtb   = (__bf16*)(ws + 25165824);            // [64][64][2048] 16 MB
    __bf16* Qb    = (__bf16*)(ws + 41943040);            // [64][2048][64] 16 MB
    __bf16* Kb    = (__bf16*)(ws + 58720256);            // 16 MB
    __bf16* Vb    = (__bf16*)(ws + 75497472);            // 16 MB
    __bf16* attO  = (__bf16*)(ws + 92274688);            // [8192][1024] 16 MB
    __bf16* ffh   = (__bf16*)(ws + 41943040);            // [8192][4096] 64 MB (reuses Qb..attO)

    transpose_cvt4<<<dim3(32, 32, 4), 256, 0, stream>>>(
        wq, wk, wv, wo, wqkvT, wqkvT + 1024 * 1024, wqkvT + 2048 * 1024, woT);
    transpose_cvt<<<dim3(128, 32), 256, 0, stream>>>(w1, w1T, 1024, 4096);
    transpose_cvt<<<dim3(32, 128), 256, 0, stream>>>(w2, w2T, 4096, 1024);

    ln_kernel<<<8192, 256, 0, stream>>>(x, l1a, l1b, xn);
    gemm_bt<0><<<dim3(24, 64), 256, 0, stream>>>(xn, wqkvT, 8192, 3072, 1024,
                                                 nullptr, nullptr, nullptr, nullptr, Qb, Kb, Vb);
    transpose_v<<<dim3(64, 2, 64), 256, 0, stream>>>(Vb, Vtb);
    attn_kernel<<<1024, 256, 0, stream>>>(Qb, Kb, Vtb, mask, attO);
    gemm_bt<1><<<dim3(8, 64), 256, 0, stream>>>(attO, woT, 8192, 1024, 1024,
                                                nullptr, x, out, nullptr, nullptr, nullptr, nullptr);
    ln_kernel<<<8192, 256, 0, stream>>>(out, l2a, l2b, xn);
    gemm_bt<2><<<dim3(32, 64), 256, 0, stream>>>(xn, w1T, 8192, 4096, 1024,
                                                 b1, nullptr, nullptr, ffh, nullptr, nullptr, nullptr);
    gemm_bt<3><<<dim3(8, 64), 256, 0, stream>>>(ffh, w2T, 8192, 1024, 4096,
                                                b2, out, out, nullptr, nullptr, nullptr, nullptr);
    (void)in_sizes; (void)n_in; (void)out_size; (void)ws_size;
}

// Round 13
// 448.301 us; speedup vs baseline: 1.6337x; 1.6337x over previous
//
#include <hip/hip_runtime.h>
#include <hip/hip_bf16.h>

typedef __bf16 bf16x8 __attribute__((ext_vector_type(8)));
typedef __bf16 bf16x4 __attribute__((ext_vector_type(4)));
typedef float  f32x4  __attribute__((ext_vector_type(4)));

#define MFMA(a, b, c) __builtin_amdgcn_mfma_f32_16x16x32_bf16((a), (b), (c), 0, 0, 0)

__device__ inline unsigned int pkbf(float a, float b) {
    __bf16 x = (__bf16)a, y = (__bf16)b;
    return (unsigned int)*(unsigned short*)&x |
           ((unsigned int)*(unsigned short*)&y << 16);
}

// ---------------------------------------------------------------------------
// Batched weight transpose + cvt for the four 1024x1024 weights (1 launch).
// ---------------------------------------------------------------------------
__global__ __launch_bounds__(256) void transpose_cvt4(
    const float* __restrict__ s0, const float* __restrict__ s1,
    const float* __restrict__ s2, const float* __restrict__ s3,
    __bf16* __restrict__ d0, __bf16* __restrict__ d1,
    __bf16* __restrict__ d2, __bf16* __restrict__ d3)
{
    __shared__ float tile[32][33];
    const int z = blockIdx.z;
    const float* src = (z == 0) ? s0 : (z == 1) ? s1 : (z == 2) ? s2 : s3;
    __bf16* dst = (z == 0) ? d0 : (z == 1) ? d1 : (z == 2) ? d2 : d3;
    const int k0 = blockIdx.y * 32, n0 = blockIdx.x * 32;
    const int t = threadIdx.x;
    const int r = t >> 5, c = t & 31;
#pragma unroll
    for (int i = 0; i < 4; ++i)
        tile[r + i * 8][c] = src[(long)(k0 + r + i * 8) * 1024 + n0 + c];
    __syncthreads();
#pragma unroll
    for (int i = 0; i < 4; ++i)
        dst[(long)(n0 + r + i * 8) * 1024 + k0 + c] = (__bf16)tile[c][r + i * 8];
}

// src f32 [K][N] -> dst bf16 [N][K]  (w1 / w2)
__global__ __launch_bounds__(256) void transpose_cvt(
    const float* __restrict__ src, __bf16* __restrict__ dst, int Kd, int Nd)
{
    __shared__ float tile[32][33];
    const int k0 = blockIdx.y * 32, n0 = blockIdx.x * 32;
    const int t = threadIdx.x;
    const int r = t >> 5, c = t & 31;
#pragma unroll
    for (int i = 0; i < 4; ++i)
        tile[r + i * 8][c] = src[(long)(k0 + r + i * 8) * Nd + n0 + c];
    __syncthreads();
#pragma unroll
    for (int i = 0; i < 4; ++i)
        dst[(long)(n0 + r + i * 8) * Kd + k0 + c] = (__bf16)tile[c][r + i * 8];
}

// V [bh][2048][64] -> Vt [bh][64][2048]
__global__ __launch_bounds__(256) void transpose_v(
    const __bf16* __restrict__ V, __bf16* __restrict__ Vt)
{
    __shared__ __bf16 tile[32][33];
    const int bh = blockIdx.z;
    const int s0 = blockIdx.x * 32, d0 = blockIdx.y * 32;
    const int t = threadIdx.x, r = t >> 5, c = t & 31;
    const __bf16* Vp = V + (long)bh * 2048 * 64;
    __bf16* Tp = Vt + (long)bh * 64 * 2048;
#pragma unroll
    for (int i = 0; i < 4; ++i)
        tile[r + i * 8][c] = Vp[(long)(s0 + r + i * 8) * 64 + d0 + c];
    __syncthreads();
#pragma unroll
    for (int i = 0; i < 4; ++i)
        Tp[(long)(d0 + r + i * 8) * 2048 + s0 + c] = tile[c][r + i * 8];
}

// ---------------------------------------------------------------------------
// LayerNorm (torch: ddof=1 std, eps added to std), f32 in, bf16 out
// ---------------------------------------------------------------------------
__global__ __launch_bounds__(256) void ln_kernel(
    const float* __restrict__ in, const float* __restrict__ ga,
    const float* __restrict__ gb, __bf16* __restrict__ out)
{
    const int row = blockIdx.x;
    const int t = threadIdx.x;
    const float4 xv = *(const float4*)(in + (long)row * 1024 + t * 4);
    float s  = xv.x + xv.y + xv.z + xv.w;
    float sq = xv.x * xv.x + xv.y * xv.y + xv.z * xv.z + xv.w * xv.w;
#pragma unroll
    for (int off = 32; off; off >>= 1) {
        s  += __shfl_xor(s, off);
        sq += __shfl_xor(sq, off);
    }
    __shared__ float red[8];
    const int w = t >> 6;
    if ((t & 63) == 0) { red[w * 2] = s; red[w * 2 + 1] = sq; }
    __syncthreads();
    s  = red[0] + red[2] + red[4] + red[6];
    sq = red[1] + red[3] + red[5] + red[7];
    const float mean = s * (1.0f / 1024.0f);
    const float var  = fmaxf((sq - s * mean) * (1.0f / 1023.0f), 0.0f);
    const float dinv = 1.0f / (sqrtf(var) + 1e-6f);
    const float4 av = *(const float4*)(ga + t * 4);
    const float4 bv = *(const float4*)(gb + t * 4);
    bf16x4 o;
    o[0] = (__bf16)((xv.x - mean) * dinv * av.x + bv.x);
    o[1] = (__bf16)((xv.y - mean) * dinv * av.y + bv.y);
    o[2] = (__bf16)((xv.z - mean) * dinv * av.z + bv.z);
    o[3] = (__bf16)((xv.w - mean) * dinv * av.w + bv.w);
    *(bf16x4*)(out + (long)row * 1024 + t * 4) = o;
}

// ---------------------------------------------------------------------------
// GEMM 128x128 (R8 reg-staged dbuf, 1 barrier/step) — best measured config.
// MODE 0: QKV scatter; 1: +resid f32; 2: +bias ReLU bf16; 3: +bias+resid f32
// ---------------------------------------------------------------------------
template <int MODE>
__global__ __launch_bounds__(256) void gemm_bt(
    const __bf16* __restrict__ A, const __bf16* __restrict__ Bt,
    int M, int N, int K,
    const float* __restrict__ bias, const float* resid,
    float* outf, __bf16* __restrict__ outb,
    __bf16* __restrict__ qb, __bf16* __restrict__ kb, __bf16* __restrict__ vb)
{
    __shared__ __align__(16) __bf16 Alds[2][128 * 32];
    __shared__ __align__(16) __bf16 Blds[2][128 * 32];

    const int t = threadIdx.x;
    const int lane = t & 63, w = t >> 6;
    const int wr = w >> 1, wc = w & 1;
    const int g = lane >> 4, l15 = lane & 15;

    const int nwg = gridDim.x * gridDim.y;
    const int hwid = blockIdx.y * gridDim.x + blockIdx.x;
    const int wid = (hwid & 7) * (nwg >> 3) + (hwid >> 3);
    const int bm = (wid / gridDim.x) * 128;
    const int bn = (wid % gridDim.x) * 128;

    const int cr = t >> 2;
    const int cc = (t & 3) * 8;
    const __bf16* Ag  = A  + (long)(bm + cr) * K + cc;
    const __bf16* Ag2 = Ag + (long)64 * K;
    const __bf16* Bg  = Bt + (long)(bn + cr) * K + cc;
    const __bf16* Bg2 = Bg + (long)64 * K;
    const int wof = cr * 32 + cc;

    f32x4 acc[4][4] = {};
    const int nk = K / 32;

    bf16x8 ra0 = *(const bf16x8*)(Ag);
    bf16x8 ra1 = *(const bf16x8*)(Ag2);
    bf16x8 rb0 = *(const bf16x8*)(Bg);
    bf16x8 rb1 = *(const bf16x8*)(Bg2);
    *(bf16x8*)(&Alds[0][wof])           = ra0;
    *(bf16x8*)(&Alds[0][wof + 64 * 32]) = ra1;
    *(bf16x8*)(&Blds[0][wof])           = rb0;
    *(bf16x8*)(&Blds[0][wof + 64 * 32]) = rb1;
    ra0 = *(const bf16x8*)(Ag  + 32);
    ra1 = *(const bf16x8*)(Ag2 + 32);
    rb0 = *(const bf16x8*)(Bg  + 32);
    rb1 = *(const bf16x8*)(Bg2 + 32);
    __syncthreads();

    for (int kt = 0; kt < nk; ++kt) {
        const int cur = kt & 1;
        if (kt + 1 < nk) {
            *(bf16x8*)(&Alds[cur ^ 1][wof])           = ra0;
            *(bf16x8*)(&Alds[cur ^ 1][wof + 64 * 32]) = ra1;
            *(bf16x8*)(&Blds[cur ^ 1][wof])           = rb0;
            *(bf16x8*)(&Blds[cur ^ 1][wof + 64 * 32]) = rb1;
            if (kt + 2 < nk) {
                const long ko = (long)(kt + 2) * 32;
                ra0 = *(const bf16x8*)(Ag  + ko);
                ra1 = *(const bf16x8*)(Ag2 + ko);
                rb0 = *(const bf16x8*)(Bg  + ko);
                rb1 = *(const bf16x8*)(Bg2 + ko);
            }
        }
        const __bf16* Ab = &Alds[cur][0];
        const __bf16* Bb = &Blds[cur][0];
        bf16x8 af[4], bfr[4];
#pragma unroll
        for (int mi = 0; mi < 4; ++mi)
            af[mi] = *(const bf16x8*)(Ab + (wr * 64 + mi * 16 + l15) * 32 + g * 8);
#pragma unroll
        for (int ni = 0; ni < 4; ++ni)
            bfr[ni] = *(const bf16x8*)(Bb + (wc * 64 + ni * 16 + l15) * 32 + g * 8);
#pragma unroll
        for (int mi = 0; mi < 4; ++mi)
#pragma unroll
            for (int ni = 0; ni < 4; ++ni)
                acc[mi][ni] = MFMA(af[mi], bfr[ni], acc[mi][ni]);
        __syncthreads();
    }

#pragma unroll
    for (int mi = 0; mi < 4; ++mi) {
#pragma unroll
        for (int ni = 0; ni < 4; ++ni) {
#pragma unroll
            for (int r = 0; r < 4; ++r) {
                const int gr = bm + wr * 64 + mi * 16 + g * 4 + r;
                const int gc = bn + wc * 64 + ni * 16 + l15;
                const float vacc = acc[mi][ni][r];
                if constexpr (MODE == 0) {
                    const int bufi = gc >> 10;
                    const int hd = gc & 1023;
                    const int h = hd >> 6, d = hd & 63;
                    const int b = gr >> 11, sx = gr & 2047;
                    __bf16* dst = (bufi == 0) ? qb : ((bufi == 1) ? kb : vb);
                    dst[((long)((b * 16 + h) * 2048 + sx)) * 64 + d] = (__bf16)vacc;
                } else if constexpr (MODE == 1) {
                    const long idx = (long)gr * N + gc;
                    outf[idx] = vacc + resid[idx];
                } else if constexpr (MODE == 2) {
                    const float y = fmaxf(vacc + bias[gc], 0.0f);
                    outb[(long)gr * N + gc] = (__bf16)y;
                } else {
                    const long idx = (long)gr * N + gc;
                    outf[idx] = vacc + bias[gc] + resid[idx];
                }
            }
        }
    }
}

// ---------------------------------------------------------------------------
// Flash attention — R8 body VERBATIM at (256,2) (the ONLY working launch
// bounds for this body: (256,4) spilled twice, R3 & R12), with one isolated
// change: XCD bh-grouping (bid&7 selects the head-octet -> per-XCD K/V
// working set 4MB = one L2; mapping verified in R7 via FETCH 139->24MB).
// ---------------------------------------------------------------------------
__global__ __launch_bounds__(256, 2) void attn_kernel(
    const __bf16* __restrict__ Q, const __bf16* __restrict__ Kk,
    const __bf16* __restrict__ Vt, const int* __restrict__ mask,
    __bf16* __restrict__ O)
{
    __shared__ __align__(16) char Klds[8192];
    __shared__ __align__(16) char Vlds[8192];
    __shared__ int mlds[64];
    __shared__ int tflag[32];

    const int t = threadIdx.x;
    const int lane = t & 63, w = t >> 6;
    const int g = lane >> 4, l15 = lane & 15;
    const int bid = blockIdx.x;
    const int bh = (bid & 7) * 8 + ((bid >> 3) >> 4);   // 8 heads per XCD
    const int qt = (bid >> 3) & 15;
    const int b = bh >> 4, h = bh & 15;
    const int q0 = qt * 128 + w * 32;

    const __bf16* Qp = Q  + (long)bh * 2048 * 64;
    const __bf16* Kp = Kk + (long)bh * 2048 * 64;
    const __bf16* Vp = Vt + (long)bh * 64 * 2048;
    const int* mp = mask + b * 2048;

    {
        const int4* mi4 = (const int4*)(mp + t * 8);
        const int4 ma = mi4[0], mb = mi4[1];
        const int ok = (ma.x && ma.y && ma.z && ma.w &&
                        mb.x && mb.y && mb.z && mb.w) ? 1 : 0;
        const unsigned long long bal = __ballot(ok);
        if ((lane & 7) == 0)
            tflag[t >> 3] = (((bal >> lane) & 0xFFull) == 0xFFull) ? 1 : 0;
    }

    bf16x8 qreg[2][2];
#pragma unroll
    for (int qf = 0; qf < 2; ++qf)
#pragma unroll
        for (int kh = 0; kh < 2; ++kh)
            qreg[qf][kh] = *(const bf16x8*)(Qp + (long)(q0 + qf * 16 + l15) * 64 + kh * 32 + g * 8);

    bf16x8 vone;
#pragma unroll
    for (int j = 0; j < 8; ++j) vone[j] = (__bf16)1.0f;

    const float Csc = 0.18033688011112042f;   // 0.125 * log2(e)
    float m2_run[2] = {-1e30f, -1e30f};
    f32x4 la[2] = {};
    f32x4 ot[2][4] = {};

    const int sr0 = t >> 3;
    const int sce = (t & 7) * 8;
    const int swz0 = sr0 * 128 + (((t & 7) * 16) ^ ((sr0 & 7) << 4));
    const int swz1 = swz0 + 32 * 128;

    bf16x8 kr0 = *(const bf16x8*)(Kp + (long)sr0 * 64 + sce);
    bf16x8 kr1 = *(const bf16x8*)(Kp + (long)(sr0 + 32) * 64 + sce);
    bf16x8 vr0 = *(const bf16x8*)(Vp + (long)sr0 * 2048 + sce);
    bf16x8 vr1 = *(const bf16x8*)(Vp + (long)(sr0 + 32) * 2048 + sce);
    int mr = (t < 64) ? mp[t] : 0;

    for (int kc = 0; kc < 32; ++kc) {
        __syncthreads();
        *(bf16x8*)(Klds + swz0) = kr0;
        *(bf16x8*)(Klds + swz1) = kr1;
        *(bf16x8*)(Vlds + swz0) = vr0;
        *(bf16x8*)(Vlds + swz1) = vr1;
        if (t < 64) mlds[t] = mr;
        __syncthreads();
        if (kc < 31) {
            const int kv0 = (kc + 1) * 64;
            kr0 = *(const bf16x8*)(Kp + (long)(kv0 + sr0) * 64 + sce);
            kr1 = *(const bf16x8*)(Kp + (long)(kv0 + sr0 + 32) * 64 + sce);
            vr0 = *(const bf16x8*)(Vp + (long)sr0 * 2048 + kv0 + sce);
            vr1 = *(const bf16x8*)(Vp + (long)(sr0 + 32) * 2048 + kv0 + sce);
            if (t < 64) mr = mp[kv0 + t];
        }
        const bool fullv = (tflag[kc] != 0);

        bf16x8 kf[4][2];
#pragma unroll
        for (int f = 0; f < 4; ++f)
#pragma unroll
            for (int dh = 0; dh < 2; ++dh)
                kf[f][dh] = *(const bf16x8*)(Klds + (f * 16 + l15) * 128 +
                                             ((dh * 64 + g * 16) ^ ((l15 & 7) << 4)));
        f32x4 sf[2][4] = {};
        __builtin_amdgcn_s_setprio(1);
#pragma unroll
        for (int qf = 0; qf < 2; ++qf)
#pragma unroll
            for (int f = 0; f < 4; ++f) {
                sf[qf][f] = MFMA(kf[f][0], qreg[qf][0], sf[qf][f]);
                sf[qf][f] = MFMA(kf[f][1], qreg[qf][1], sf[qf][f]);
            }
        __builtin_amdgcn_s_setprio(0);

        bf16x8 av[4][2];
#pragma unroll
        for (int df = 0; df < 4; ++df) {
            const int row = (df * 16 + l15) * 128;
            const int sx = (l15 & 7) << 4;
#pragma unroll
            for (int hh = 0; hh < 2; ++hh) {
                const bf16x4 lo = *(const bf16x4*)(Vlds + row + ((hh * 64 + g * 8) ^ sx));
                const bf16x4 hi = *(const bf16x4*)(Vlds + row + ((hh * 64 + 32 + g * 8) ^ sx));
                bf16x8 a;
                a[0] = lo[0]; a[1] = lo[1]; a[2] = lo[2]; a[3] = lo[3];
                a[4] = hi[0]; a[5] = hi[1]; a[6] = hi[2]; a[7] = hi[3];
                av[df][hh] = a;
            }
        }

#pragma unroll
        for (int qf = 0; qf < 2; ++qf) {
            float s[16];
            if (fullv) {
#pragma unroll
                for (int i = 0; i < 16; ++i) s[i] = sf[qf][i >> 2][i & 3];
            } else {
                int mvv[16];
#pragma unroll
                for (int f = 0; f < 4; ++f) {
                    const int4 mq = *(const int4*)&mlds[f * 16 + g * 4];
                    mvv[f * 4 + 0] = mq.x; mvv[f * 4 + 1] = mq.y;
                    mvv[f * 4 + 2] = mq.z; mvv[f * 4 + 3] = mq.w;
                }
#pragma unroll
                for (int i = 0; i < 16; ++i)
                    s[i] = (mvv[i] == 0) ? -1e9f : sf[qf][i >> 2][i & 3];
            }
            float m01 = fmaxf(s[0], s[1]),   m23 = fmaxf(s[2], s[3]);
            float m45 = fmaxf(s[4], s[5]),   m67 = fmaxf(s[6], s[7]);
            float m89 = fmaxf(s[8], s[9]),   mab = fmaxf(s[10], s[11]);
            float mcd = fmaxf(s[12], s[13]), mef = fmaxf(s[14], s[15]);
            float mx = fmaxf(fmaxf(fmaxf(m01, m23), fmaxf(m45, m67)),
                             fmaxf(fmaxf(m89, mab), fmaxf(mcd, mef)));
            mx = fmaxf(mx, __shfl_xor(mx, 16));
            mx = fmaxf(mx, __shfl_xor(mx, 32));
            const float m2 = mx * Csc;
            if (!__all(m2 - m2_run[qf] <= 8.0f)) {
                const float m2n = fmaxf(m2_run[qf], m2);
                const float alpha = __builtin_amdgcn_exp2f(m2_run[qf] - m2n);
#pragma unroll
                for (int r = 0; r < 4; ++r) la[qf][r] *= alpha;
#pragma unroll
                for (int df = 0; df < 4; ++df)
#pragma unroll
                    for (int r = 0; r < 4; ++r) ot[qf][df][r] *= alpha;
                m2_run[qf] = m2n;
            }
            const float nm2 = -m2_run[qf];
            float p[16];
#pragma unroll
            for (int i = 0; i < 16; ++i)
                p[i] = __builtin_amdgcn_exp2f(__builtin_fmaf(s[i], Csc, nm2));

#pragma unroll
            for (int hh = 0; hh < 2; ++hh) {
                unsigned int pu[4] = {pkbf(p[hh * 8 + 0], p[hh * 8 + 1]),
                                      pkbf(p[hh * 8 + 2], p[hh * 8 + 3]),
                                      pkbf(p[hh * 8 + 4], p[hh * 8 + 5]),
                                      pkbf(p[hh * 8 + 6], p[hh * 8 + 7])};
                bf16x8 pf = *(bf16x8*)pu;   // slot j = P[sigma(g,j)][q=l15]
                __builtin_amdgcn_s_setprio(1);
#pragma unroll
                for (int df = 0; df < 4; ++df)
                    ot[qf][df] = MFMA(av[df][hh], pf, ot[qf][df]);
                la[qf] = MFMA(vone, pf, la[qf]);
                __builtin_amdgcn_s_setprio(0);
            }
        }
    }

#pragma unroll
    for (int qf = 0; qf < 2; ++qf) {
        const float inv = 1.0f / la[qf][0];
        const int q = q0 + qf * 16 + l15;
        __bf16* orow = O + (long)(b * 2048 + q) * 1024 + h * 64;
#pragma unroll
        for (int df = 0; df < 4; ++df)
#pragma unroll
            for (int rp = 0; rp < 2; ++rp) {
                const int d = df * 16 + g * 4 + rp * 2;
                *(unsigned int*)(orow + d) =
                    pkbf(ot[qf][df][rp * 2] * inv, ot[qf][df][rp * 2 + 1] * inv);
            }
    }
}

// ---------------------------------------------------------------------------
extern "C" void kernel_launch(void* const* d_in, const int* in_sizes, int n_in,
                              void* d_out, int out_size, void* d_ws, size_t ws_size,
                              hipStream_t stream)
{
    const float* x    = (const float*)d_in[0];
    const int*   mask = (const int*)  d_in[1];
    const float* wq   = (const float*)d_in[2];
    const float* wk   = (const float*)d_in[3];
    const float* wv   = (const float*)d_in[4];
    const float* wo   = (const float*)d_in[5];
    const float* w1   = (const float*)d_in[6];
    const float* b1   = (const float*)d_in[7];
    const float* w2   = (const float*)d_in[8];
    const float* b2   = (const float*)d_in[9];
    const float* l1a  = (const float*)d_in[10];
    const float* l1b  = (const float*)d_in[11];
    const float* l2a  = (const float*)d_in[12];
    const float* l2b  = (const float*)d_in[13];
    float* out = (float*)d_out;

    char* ws = (char*)d_ws;
    __bf16* wqkvT = (__bf16*)(ws);                       // [3072][1024]  6 MB
    __bf16* woT   = (__bf16*)(ws + 6291456);             // [1024][1024]  2 MB
    __bf16* w1T   = (__bf16*)(ws + 8388608);             // [4096][1024]  8 MB
    __bf16* w2T   = (__bf16*)(ws + 16777216);            // [1024][4096]  8 MB
    __bf16* xn    = (__bf16*)(ws + 25165824);            // [8192][1024] 16 MB (doubles as Vt)
    __bf16* Vtb   = (__bf16*)(ws + 25165824);            // [64][64][2048] 16 MB
    __bf16* Qb    = (__bf16*)(ws + 41943040);            // [64][2048][64] 16 MB
    __bf16* Kb    = (__bf16*)(ws + 58720256);            // 16 MB
    __bf16* Vb    = (__bf16*)(ws + 75497472);            // 16 MB
    __bf16* attO  = (__bf16*)(ws + 92274688);            // [8192][1024] 16 MB
    __bf16* ffh   = (__bf16*)(ws + 41943040);            // [8192][4096] 64 MB (reuses Qb..attO)

    transpose_cvt4<<<dim3(32, 32, 4), 256, 0, stream>>>(
        wq, wk, wv, wo, wqkvT, wqkvT + 1024 * 1024, wqkvT + 2048 * 1024, woT);
    transpose_cvt<<<dim3(128, 32), 256, 0, stream>>>(w1, w1T, 1024, 4096);
    transpose_cvt<<<dim3(32, 128), 256, 0, stream>>>(w2, w2T, 4096, 1024);

    ln_kernel<<<8192, 256, 0, stream>>>(x, l1a, l1b, xn);
    gemm_bt<0><<<dim3(24, 64), 256, 0, stream>>>(xn, wqkvT, 8192, 3072, 1024,
                                                 nullptr, nullptr, nullptr, nullptr, Qb, Kb, Vb);
    transpose_v<<<dim3(64, 2, 64), 256, 0, stream>>>(Vb, Vtb);
    attn_kernel<<<1024, 256, 0, stream>>>(Qb, Kb, Vtb, mask, attO);
    gemm_bt<1><<<dim3(8, 64), 256, 0, stream>>>(attO, woT, 8192, 1024, 1024,
                                                nullptr, x, out, nullptr, nullptr, nullptr, nullptr);
    ln_kernel<<<8192, 256, 0, stream>>>(out, l2a, l2b, xn);
    gemm_bt<2><<<dim3(32, 64), 256, 0, stream>>>(xn, w1T, 8192, 4096, 1024,
                                                 b1, nullptr, nullptr, ffh, nullptr, nullptr, nullptr);
    gemm_bt<3><<<dim3(8, 64), 256, 0, stream>>>(ffh, w2T, 8192, 1024, 4096,
                                                b2, out, out, nullptr, nullptr, nullptr, nullptr);
    (void)in_sizes; (void)n_in; (void)out_size; (void)ws_size;
}